// Round 1
// baseline (4111.993 us; speedup 1.0000x reference)
//
#include <hip/hip_runtime.h>

// Problem constants (fixed by reference)
#define IN_DIM  256
#define HID_DIM 256
#define H2_DIM  128
#define EMB_DIM 64
#define K_CODES 4096
#define EPS_BN  1e-5f

// ---------------------------------------------------------------------------
// Kernel 0: half squared norms of codebook rows: norms[c] = 0.5*||e_c||^2
// ---------------------------------------------------------------------------
__global__ __launch_bounds__(256) void k_norms(const float* __restrict__ cb,
                                               float* __restrict__ norms) {
    int c = blockIdx.x * 256 + threadIdx.x;  // exactly 4096 threads
    const float4* row = reinterpret_cast<const float4*>(cb + (size_t)c * EMB_DIM);
    float s = 0.f;
#pragma unroll
    for (int i = 0; i < EMB_DIM / 4; ++i) {
        float4 v = row[i];
        s += v.x * v.x + v.y * v.y + v.z * v.z + v.w * v.w;
    }
    norms[c] = 0.5f * s;
}

// ---------------------------------------------------------------------------
// Generic global->LDS tile copy, float4 granularity, 256 threads.
// M rows x Kc cols, global row stride LDG, LDS row stride LDL (padded, %4==0).
// ---------------------------------------------------------------------------
template <int M, int Kc, int LDG, int LDL>
__device__ __forceinline__ void g2l(const float* __restrict__ src, float* dst, int tid) {
    constexpr int NF4 = M * Kc / 4;
    constexpr int K4  = Kc / 4;
    static_assert(NF4 % 256 == 0, "tile not divisible");
#pragma unroll
    for (int it = 0; it < NF4 / 256; ++it) {
        int i   = it * 256 + tid;
        int row = i / K4;
        int c4  = i % K4;
        float4 v = *reinterpret_cast<const float4*>(src + row * LDG + c4 * 4);
        *reinterpret_cast<float4*>(dst + row * LDL + c4 * 4) = v;
    }
}

// ---------------------------------------------------------------------------
// Kernel 1: fused encoder. 64 rows per block, 256 threads.
//   h1 = relu(BN(x@W1^T + b1)); h2 = relu(h1@W2^T + b2); z = tanh(h2@W3^T + b3)
// Thread grid: rg = tid&7 (8 row-groups), cg = tid>>3 (32 col-groups).
// Thread micro-tile rows: r = ir*8+rg (strided -> conflict-free LDS reads).
// LDS strides padded +4 floats (bank offset 4/row, float4 alignment kept).
// ---------------------------------------------------------------------------
__global__ __launch_bounds__(256, 2) void k_encoder(
    const float* __restrict__ x,  const float* __restrict__ W1, const float* __restrict__ b1,
    const float* __restrict__ gm, const float* __restrict__ bt,
    const float* __restrict__ mu, const float* __restrict__ vr,
    const float* __restrict__ W2, const float* __restrict__ b2,
    const float* __restrict__ W3, const float* __restrict__ b3,
    float* __restrict__ Z) {
    __shared__ __align__(16) float lds[16896];  // 67.6 KB union buffer -> 2 blocks/CU
    const int tid = threadIdx.x;
    const int rg  = tid & 7;
    const int cg  = tid >> 3;
    const int r0  = blockIdx.x * 64;

    // ---------------- Stage 1: h1 = x @ W1^T  (k = 256, chunks of 32) -------
    float acc1[8][8];
#pragma unroll
    for (int a = 0; a < 8; ++a)
#pragma unroll
        for (int b = 0; b < 8; ++b) acc1[a][b] = 0.f;

    float* xbuf  = lds;          // [64][36]
    float* w1buf = lds + 2304;   // [256][36]

    for (int kc = 0; kc < 8; ++kc) {
        __syncthreads();
        g2l<64, 32, IN_DIM, 36>(x + (size_t)r0 * IN_DIM + kc * 32, xbuf, tid);
        g2l<256, 32, IN_DIM, 36>(W1 + kc * 32, w1buf, tid);
        __syncthreads();
#pragma unroll
        for (int k4 = 0; k4 < 8; ++k4) {
            float4 xf[8], wf[8];
#pragma unroll
            for (int ir = 0; ir < 8; ++ir)
                xf[ir] = *reinterpret_cast<float4*>(xbuf + (ir * 8 + rg) * 36 + k4 * 4);
#pragma unroll
            for (int ij = 0; ij < 8; ++ij)
                wf[ij] = *reinterpret_cast<float4*>(w1buf + (ij * 32 + cg) * 36 + k4 * 4);
#pragma unroll
            for (int ir = 0; ir < 8; ++ir)
#pragma unroll
                for (int ij = 0; ij < 8; ++ij)
                    acc1[ir][ij] += xf[ir].x * wf[ij].x + xf[ir].y * wf[ij].y +
                                    xf[ir].z * wf[ij].z + xf[ir].w * wf[ij].w;
        }
    }

    // BN (eval stats) + ReLU in registers: h1 = relu(acc*sc + sh)
    float h1v[8][8];
#pragma unroll
    for (int ij = 0; ij < 8; ++ij) {
        int j = ij * 32 + cg;
        float sc = gm[j] / sqrtf(vr[j] + EPS_BN);
        float sh = (b1[j] - mu[j]) * sc + bt[j];
#pragma unroll
        for (int ir = 0; ir < 8; ++ir) {
            float v = acc1[ir][ij] * sc + sh;
            h1v[ir][ij] = v > 0.f ? v : 0.f;
        }
    }

    // ---------------- Stage 2: h2 = h1 @ W2^T (k = 256, j-chunks of 64) -----
    float acc2[8][4];
#pragma unroll
    for (int a = 0; a < 8; ++a)
#pragma unroll
        for (int b = 0; b < 4; ++b) acc2[a][b] = 0.f;

    float* h1c   = lds;          // [64][68]
    float* w2buf = lds + 4352;   // [128][68]

    for (int jc = 0; jc < 4; ++jc) {
        __syncthreads();
#pragma unroll
        for (int q = 0; q < 2; ++q) {
            int ij = jc * 2 + q;
            int jl = q * 32 + cg;
#pragma unroll
            for (int ir = 0; ir < 8; ++ir)
                h1c[(ir * 8 + rg) * 68 + jl] = h1v[ir][ij];
        }
        g2l<128, 64, HID_DIM, 68>(W2 + jc * 64, w2buf, tid);
        __syncthreads();
#pragma unroll
        for (int k4 = 0; k4 < 16; ++k4) {
            float4 hf[8], wf[4];
#pragma unroll
            for (int ir = 0; ir < 8; ++ir)
                hf[ir] = *reinterpret_cast<float4*>(h1c + (ir * 8 + rg) * 68 + k4 * 4);
#pragma unroll
            for (int ij = 0; ij < 4; ++ij)
                wf[ij] = *reinterpret_cast<float4*>(w2buf + (ij * 32 + cg) * 68 + k4 * 4);
#pragma unroll
            for (int ir = 0; ir < 8; ++ir)
#pragma unroll
                for (int ij = 0; ij < 4; ++ij)
                    acc2[ir][ij] += hf[ir].x * wf[ij].x + hf[ir].y * wf[ij].y +
                                    hf[ir].z * wf[ij].z + hf[ir].w * wf[ij].w;
        }
    }

    // ReLU(+b2), hand off to LDS for stage 3
    __syncthreads();
    float* h2buf = lds;          // [64][132]
    float* w3buf = lds + 8448;   // [64][132]
#pragma unroll
    for (int ij = 0; ij < 4; ++ij) {
        int j2 = ij * 32 + cg;
        float bias = b2[j2];
#pragma unroll
        for (int ir = 0; ir < 8; ++ir) {
            float v = acc2[ir][ij] + bias;
            h2buf[(ir * 8 + rg) * 132 + j2] = v > 0.f ? v : 0.f;
        }
    }
    g2l<64, 128, H2_DIM, 132>(W3, w3buf, tid);
    __syncthreads();

    // ---------------- Stage 3: z = tanh(h2 @ W3^T + b3) (k = 128) -----------
    float acc3[8][2];
#pragma unroll
    for (int a = 0; a < 8; ++a) { acc3[a][0] = 0.f; acc3[a][1] = 0.f; }
#pragma unroll
    for (int k4 = 0; k4 < 32; ++k4) {
        float4 hf[8], wf[2];
#pragma unroll
        for (int ir = 0; ir < 8; ++ir)
            hf[ir] = *reinterpret_cast<float4*>(h2buf + (ir * 8 + rg) * 132 + k4 * 4);
#pragma unroll
        for (int ij = 0; ij < 2; ++ij)
            wf[ij] = *reinterpret_cast<float4*>(w3buf + (ij * 32 + cg) * 132 + k4 * 4);
#pragma unroll
        for (int ir = 0; ir < 8; ++ir)
#pragma unroll
            for (int ij = 0; ij < 2; ++ij)
                acc3[ir][ij] += hf[ir].x * wf[ij].x + hf[ir].y * wf[ij].y +
                                hf[ir].z * wf[ij].z + hf[ir].w * wf[ij].w;
    }
#pragma unroll
    for (int ij = 0; ij < 2; ++ij) {
        int j3 = ij * 32 + cg;
        float bias = b3[j3];
#pragma unroll
        for (int ir = 0; ir < 8; ++ir) {
            float zv = tanhf(acc3[ir][ij] + bias);
            Z[(size_t)(r0 + ir * 8 + rg) * EMB_DIM + j3] = zv;
        }
    }
}

// ---------------------------------------------------------------------------
// Kernel 2: nearest-code argmin. 64 rows/block, 128-code chunks.
// score(r,c) = 0.5*||e_c||^2 - z_r . e_c   (||z||^2 dropped: row-constant)
// ---------------------------------------------------------------------------
__global__ __launch_bounds__(256, 2) void k_argmin(
    const float* __restrict__ Z, const float* __restrict__ cb,
    const float* __restrict__ norms, int* __restrict__ out) {
    __shared__ __align__(16) float lds[13184];  // 52.7 KB
    float* zbuf = lds;           // [64][68]
    float* ebuf = lds + 4352;    // [128][68]
    float* nbuf = lds + 13056;   // [128]
    const int tid = threadIdx.x;
    const int rg  = tid & 7;
    const int cg  = tid >> 3;
    const int r0  = blockIdx.x * 64;

    g2l<64, 64, EMB_DIM, 68>(Z + (size_t)r0 * EMB_DIM, zbuf, tid);

    float bv[8];
    int   bi[8];
#pragma unroll
    for (int ir = 0; ir < 8; ++ir) { bv[ir] = 3.4e38f; bi[ir] = 0; }

    for (int ch = 0; ch < K_CODES / 128; ++ch) {
        __syncthreads();
        g2l<128, 64, EMB_DIM, 68>(cb + (size_t)ch * 128 * EMB_DIM, ebuf, tid);
        if (tid < 128) nbuf[tid] = norms[ch * 128 + tid];
        __syncthreads();

        float acc[8][4];
#pragma unroll
        for (int a = 0; a < 8; ++a)
#pragma unroll
            for (int b = 0; b < 4; ++b) acc[a][b] = 0.f;

#pragma unroll
        for (int k4 = 0; k4 < 16; ++k4) {
            float4 zf[8], ef[4];
#pragma unroll
            for (int ir = 0; ir < 8; ++ir)
                zf[ir] = *reinterpret_cast<float4*>(zbuf + (ir * 8 + rg) * 68 + k4 * 4);
#pragma unroll
            for (int ic = 0; ic < 4; ++ic)
                ef[ic] = *reinterpret_cast<float4*>(ebuf + (ic * 32 + cg) * 68 + k4 * 4);
#pragma unroll
            for (int ir = 0; ir < 8; ++ir)
#pragma unroll
                for (int ic = 0; ic < 4; ++ic)
                    acc[ir][ic] += zf[ir].x * ef[ic].x + zf[ir].y * ef[ic].y +
                                   zf[ir].z * ef[ic].z + zf[ir].w * ef[ic].w;
        }

#pragma unroll
        for (int ic = 0; ic < 4; ++ic) {
            int cl = ic * 32 + cg;
            float nh = nbuf[cl];
            int cglob = ch * 128 + cl;
#pragma unroll
            for (int ir = 0; ir < 8; ++ir) {
                float s = nh - acc[ir][ic];
                bool lt = s < bv[ir];
                bv[ir] = lt ? s : bv[ir];
                bi[ir] = lt ? cglob : bi[ir];
            }
        }
    }

    // Cross-thread (cg) reduction through LDS; stride 33 -> conflict-free scan.
    __syncthreads();
    float* redv = lds;                                  // [64][33]
    int*   redi = reinterpret_cast<int*>(lds + 2112);   // [64][33]
#pragma unroll
    for (int ir = 0; ir < 8; ++ir) {
        int r = ir * 8 + rg;
        redv[r * 33 + cg] = bv[ir];
        redi[r * 33 + cg] = bi[ir];
    }
    __syncthreads();
    if (tid < 64) {
        float v  = redv[tid * 33];
        int   ix = redi[tid * 33];
#pragma unroll
        for (int j = 1; j < 32; ++j) {
            float vj = redv[tid * 33 + j];
            int   ij = redi[tid * 33 + j];
            if (vj < v) { v = vj; ix = ij; }
        }
        out[r0 + tid] = ix;
    }
}

// ---------------------------------------------------------------------------
extern "C" void kernel_launch(void* const* d_in, const int* in_sizes, int n_in,
                              void* d_out, int out_size, void* d_ws, size_t ws_size,
                              hipStream_t stream) {
    (void)in_sizes; (void)n_in; (void)out_size; (void)ws_size;
    const float* x  = (const float*)d_in[0];
    const float* W1 = (const float*)d_in[1];
    const float* b1 = (const float*)d_in[2];
    const float* gm = (const float*)d_in[3];
    const float* bt = (const float*)d_in[4];
    const float* mu = (const float*)d_in[5];
    const float* vr = (const float*)d_in[6];
    const float* W2 = (const float*)d_in[7];
    const float* b2 = (const float*)d_in[8];
    const float* W3 = (const float*)d_in[9];
    const float* b3 = (const float*)d_in[10];
    const float* cb = (const float*)d_in[11];

    float* norms = (float*)d_ws;                       // 4096 floats (16 KB)
    float* Z     = (float*)((char*)d_ws + 16384);      // 65536 x 64 (16 MB)
    int*   out   = (int*)d_out;

    const int B = in_sizes[0] / IN_DIM;                // 65536

    k_norms<<<K_CODES / 256, 256, 0, stream>>>(cb, norms);
    k_encoder<<<B / 64, 256, 0, stream>>>(x, W1, b1, gm, bt, mu, vr, W2, b2, W3, b3, Z);
    k_argmin<<<B / 64, 256, 0, stream>>>(Z, cb, norms, out);
}

// Round 2
// 2933.427 us; speedup vs baseline: 1.4018x; 1.4018x over previous
//
#include <hip/hip_runtime.h>

// Problem constants (fixed by reference)
#define IN_DIM  256
#define HID_DIM 256
#define H2_DIM  128
#define EMB_DIM 64
#define K_CODES 4096
#define EPS_BN  1e-5f

// ---------------------------------------------------------------------------
// Kernel 0: half squared norms of codebook rows: norms[c] = 0.5*||e_c||^2
// ---------------------------------------------------------------------------
__global__ __launch_bounds__(256) void k_norms(const float* __restrict__ cb,
                                               float* __restrict__ norms) {
    int c = blockIdx.x * 256 + threadIdx.x;  // exactly 4096 threads
    const float4* row = reinterpret_cast<const float4*>(cb + (size_t)c * EMB_DIM);
    float s = 0.f;
#pragma unroll
    for (int i = 0; i < EMB_DIM / 4; ++i) {
        float4 v = row[i];
        s += v.x * v.x + v.y * v.y + v.z * v.z + v.w * v.w;
    }
    norms[c] = 0.5f * s;
}

// ---------------------------------------------------------------------------
// Generic global->LDS tile copy, float4 granularity, 256 threads.
// M rows x Kc cols, global row stride LDG, LDS row stride LDL (%4==0).
// ---------------------------------------------------------------------------
template <int M, int Kc, int LDG, int LDL>
__device__ __forceinline__ void g2l(const float* __restrict__ src, float* dst, int tid) {
    constexpr int NF4 = M * Kc / 4;
    constexpr int K4  = Kc / 4;
    static_assert(NF4 % 256 == 0, "tile not divisible");
#pragma unroll
    for (int it = 0; it < NF4 / 256; ++it) {
        int i   = it * 256 + tid;
        int row = i / K4;
        int c4  = i % K4;
        float4 v = *reinterpret_cast<const float4*>(src + row * LDG + c4 * 4);
        *reinterpret_cast<float4*>(dst + row * LDL + c4 * 4) = v;
    }
}

// ---------------------------------------------------------------------------
// Kernel 1: fused encoder. 32 rows per block, 256 threads, micro-tile 4x8.
//   h1 = relu(BN(x@W1^T + b1)); h2 = relu(h1@W2^T + b2); z = tanh(h2@W3^T + b3)
// rg = tid&7 (8 row-groups; rows r = ir*8+rg, ir<4), cg = tid>>3 (32 col-grps).
// LDS strides 36/260/132: all ==4 mod 32 floats -> conflict-free b128 reads.
// Peak live regs (stage 1): acc 32 + xf 16 + wf 32 + addr ~= 100 -> no spill
// under __launch_bounds__(256,3) (cap ~170). LDS union 51.7 KB -> 3 blk/CU.
// ---------------------------------------------------------------------------
__global__ __launch_bounds__(256, 3) void k_encoder(
    const float* __restrict__ x,  const float* __restrict__ W1, const float* __restrict__ b1,
    const float* __restrict__ gm, const float* __restrict__ bt,
    const float* __restrict__ mu, const float* __restrict__ vr,
    const float* __restrict__ W2, const float* __restrict__ b2,
    const float* __restrict__ W3, const float* __restrict__ b3,
    float* __restrict__ Z) {
    __shared__ __align__(16) float lds[12928];  // 51.7 KB union
    const int tid = threadIdx.x;
    const int rg  = tid & 7;
    const int cg  = tid >> 3;
    const int r0  = blockIdx.x * 32;

    // ---------------- Stage 1: h1 = x @ W1^T  (k = 256, chunks of 32) -------
    float acc1[4][8];
#pragma unroll
    for (int a = 0; a < 4; ++a)
#pragma unroll
        for (int b = 0; b < 8; ++b) acc1[a][b] = 0.f;

    float* xbuf  = lds;          // [32][36]
    float* w1buf = lds + 1152;   // [256][36]

    for (int kc = 0; kc < 8; ++kc) {
        __syncthreads();
        g2l<32, 32, IN_DIM, 36>(x + (size_t)r0 * IN_DIM + kc * 32, xbuf, tid);
        g2l<256, 32, IN_DIM, 36>(W1 + kc * 32, w1buf, tid);
        __syncthreads();
#pragma unroll
        for (int k4 = 0; k4 < 8; ++k4) {
            float4 xf[4], wf[8];
#pragma unroll
            for (int ir = 0; ir < 4; ++ir)
                xf[ir] = *reinterpret_cast<float4*>(xbuf + (ir * 8 + rg) * 36 + k4 * 4);
#pragma unroll
            for (int ij = 0; ij < 8; ++ij)
                wf[ij] = *reinterpret_cast<float4*>(w1buf + (ij * 32 + cg) * 36 + k4 * 4);
#pragma unroll
            for (int ir = 0; ir < 4; ++ir)
#pragma unroll
                for (int ij = 0; ij < 8; ++ij)
                    acc1[ir][ij] += xf[ir].x * wf[ij].x + xf[ir].y * wf[ij].y +
                                    xf[ir].z * wf[ij].z + xf[ir].w * wf[ij].w;
        }
    }

    // BN (eval stats) + ReLU in registers (in place), then park h1 in LDS.
#pragma unroll
    for (int ij = 0; ij < 8; ++ij) {
        int j = ij * 32 + cg;
        float sc = gm[j] / sqrtf(vr[j] + EPS_BN);
        float sh = (b1[j] - mu[j]) * sc + bt[j];
#pragma unroll
        for (int ir = 0; ir < 4; ++ir) {
            float v = acc1[ir][ij] * sc + sh;
            acc1[ir][ij] = v > 0.f ? v : 0.f;
        }
    }

    __syncthreads();  // all stage-1 LDS reads done before overwrite
    float* h1buf = lds;          // [32][260], resident through stage 2
    float* w2buf = lds + 8320;   // [128][36]
#pragma unroll
    for (int ij = 0; ij < 8; ++ij)
#pragma unroll
        for (int ir = 0; ir < 4; ++ir)
            h1buf[(ir * 8 + rg) * 260 + ij * 32 + cg] = acc1[ir][ij];

    // ---------------- Stage 2: h2 = h1 @ W2^T (k = 256, chunks of 32) -------
    float acc2[4][4];
#pragma unroll
    for (int a = 0; a < 4; ++a)
#pragma unroll
        for (int b = 0; b < 4; ++b) acc2[a][b] = 0.f;

    for (int kc = 0; kc < 8; ++kc) {
        __syncthreads();  // first iter: h1 writes visible; later: w2buf reads done
        g2l<128, 32, HID_DIM, 36>(W2 + kc * 32, w2buf, tid);
        __syncthreads();
#pragma unroll
        for (int k4 = 0; k4 < 8; ++k4) {
            float4 hf[4], wf[4];
#pragma unroll
            for (int ir = 0; ir < 4; ++ir)
                hf[ir] = *reinterpret_cast<float4*>(h1buf + (ir * 8 + rg) * 260 + kc * 32 + k4 * 4);
#pragma unroll
            for (int ij = 0; ij < 4; ++ij)
                wf[ij] = *reinterpret_cast<float4*>(w2buf + (ij * 32 + cg) * 36 + k4 * 4);
#pragma unroll
            for (int ir = 0; ir < 4; ++ir)
#pragma unroll
                for (int ij = 0; ij < 4; ++ij)
                    acc2[ir][ij] += hf[ir].x * wf[ij].x + hf[ir].y * wf[ij].y +
                                    hf[ir].z * wf[ij].z + hf[ir].w * wf[ij].w;
        }
    }

    // ReLU(+b2) -> LDS, stage W3, compute stage 3.
    __syncthreads();  // all stage-2 reads of h1buf/w2buf done
    float* h2buf = lds;          // [32][132]
    float* w3buf = lds + 4224;   // [64][132]
#pragma unroll
    for (int ij = 0; ij < 4; ++ij) {
        int j2 = ij * 32 + cg;
        float bias = b2[j2];
#pragma unroll
        for (int ir = 0; ir < 4; ++ir) {
            float v = acc2[ir][ij] + bias;
            h2buf[(ir * 8 + rg) * 132 + j2] = v > 0.f ? v : 0.f;
        }
    }
    g2l<64, 128, H2_DIM, 132>(W3, w3buf, tid);
    __syncthreads();

    // ---------------- Stage 3: z = tanh(h2 @ W3^T + b3) (k = 128) -----------
    float acc3[4][2];
#pragma unroll
    for (int a = 0; a < 4; ++a) { acc3[a][0] = 0.f; acc3[a][1] = 0.f; }
#pragma unroll
    for (int k4 = 0; k4 < 32; ++k4) {
        float4 hf[4], wf[2];
#pragma unroll
        for (int ir = 0; ir < 4; ++ir)
            hf[ir] = *reinterpret_cast<float4*>(h2buf + (ir * 8 + rg) * 132 + k4 * 4);
#pragma unroll
        for (int ij = 0; ij < 2; ++ij)
            wf[ij] = *reinterpret_cast<float4*>(w3buf + (ij * 32 + cg) * 132 + k4 * 4);
#pragma unroll
        for (int ir = 0; ir < 4; ++ir)
#pragma unroll
            for (int ij = 0; ij < 2; ++ij)
                acc3[ir][ij] += hf[ir].x * wf[ij].x + hf[ir].y * wf[ij].y +
                                hf[ir].z * wf[ij].z + hf[ir].w * wf[ij].w;
    }
#pragma unroll
    for (int ij = 0; ij < 2; ++ij) {
        int j3 = ij * 32 + cg;
        float bias = b3[j3];
#pragma unroll
        for (int ir = 0; ir < 4; ++ir) {
            float zv = tanhf(acc3[ir][ij] + bias);
            Z[(size_t)(r0 + ir * 8 + rg) * EMB_DIM + j3] = zv;
        }
    }
}

// ---------------------------------------------------------------------------
// Kernel 2: nearest-code argmin. 64 rows/block, 128-code chunks.
// score(r,c) = 0.5*||e_c||^2 - z_r . e_c   (||z||^2 dropped: row-constant)
// ---------------------------------------------------------------------------
__global__ __launch_bounds__(256, 2) void k_argmin(
    const float* __restrict__ Z, const float* __restrict__ cb,
    const float* __restrict__ norms, int* __restrict__ out) {
    __shared__ __align__(16) float lds[13184];  // 52.7 KB
    float* zbuf = lds;           // [64][68]
    float* ebuf = lds + 4352;    // [128][68]
    float* nbuf = lds + 13056;   // [128]
    const int tid = threadIdx.x;
    const int rg  = tid & 7;
    const int cg  = tid >> 3;
    const int r0  = blockIdx.x * 64;

    g2l<64, 64, EMB_DIM, 68>(Z + (size_t)r0 * EMB_DIM, zbuf, tid);

    float bv[8];
    int   bi[8];
#pragma unroll
    for (int ir = 0; ir < 8; ++ir) { bv[ir] = 3.4e38f; bi[ir] = 0; }

    for (int ch = 0; ch < K_CODES / 128; ++ch) {
        __syncthreads();
        g2l<128, 64, EMB_DIM, 68>(cb + (size_t)ch * 128 * EMB_DIM, ebuf, tid);
        if (tid < 128) nbuf[tid] = norms[ch * 128 + tid];
        __syncthreads();

        float acc[8][4];
#pragma unroll
        for (int a = 0; a < 8; ++a)
#pragma unroll
            for (int b = 0; b < 4; ++b) acc[a][b] = 0.f;

#pragma unroll
        for (int k4 = 0; k4 < 16; ++k4) {
            float4 zf[8], ef[4];
#pragma unroll
            for (int ir = 0; ir < 8; ++ir)
                zf[ir] = *reinterpret_cast<float4*>(zbuf + (ir * 8 + rg) * 68 + k4 * 4);
#pragma unroll
            for (int ic = 0; ic < 4; ++ic)
                ef[ic] = *reinterpret_cast<float4*>(ebuf + (ic * 32 + cg) * 68 + k4 * 4);
#pragma unroll
            for (int ir = 0; ir < 8; ++ir)
#pragma unroll
                for (int ic = 0; ic < 4; ++ic)
                    acc[ir][ic] += zf[ir].x * ef[ic].x + zf[ir].y * ef[ic].y +
                                   zf[ir].z * ef[ic].z + zf[ir].w * ef[ic].w;
        }

#pragma unroll
        for (int ic = 0; ic < 4; ++ic) {
            int cl = ic * 32 + cg;
            float nh = nbuf[cl];
            int cglob = ch * 128 + cl;
#pragma unroll
            for (int ir = 0; ir < 8; ++ir) {
                float s = nh - acc[ir][ic];
                bool lt = s < bv[ir];
                bv[ir] = lt ? s : bv[ir];
                bi[ir] = lt ? cglob : bi[ir];
            }
        }
    }

    // Cross-thread (cg) reduction through LDS; stride 33 -> conflict-free scan.
    __syncthreads();
    float* redv = lds;                                  // [64][33]
    int*   redi = reinterpret_cast<int*>(lds + 2112);   // [64][33]
#pragma unroll
    for (int ir = 0; ir < 8; ++ir) {
        int r = ir * 8 + rg;
        redv[r * 33 + cg] = bv[ir];
        redi[r * 33 + cg] = bi[ir];
    }
    __syncthreads();
    if (tid < 64) {
        float v  = redv[tid * 33];
        int   ix = redi[tid * 33];
#pragma unroll
        for (int j = 1; j < 32; ++j) {
            float vj = redv[tid * 33 + j];
            int   ij = redi[tid * 33 + j];
            if (vj < v) { v = vj; ix = ij; }
        }
        out[r0 + tid] = ix;
    }
}

// ---------------------------------------------------------------------------
extern "C" void kernel_launch(void* const* d_in, const int* in_sizes, int n_in,
                              void* d_out, int out_size, void* d_ws, size_t ws_size,
                              hipStream_t stream) {
    (void)n_in; (void)out_size; (void)ws_size;
    const float* x  = (const float*)d_in[0];
    const float* W1 = (const float*)d_in[1];
    const float* b1 = (const float*)d_in[2];
    const float* gm = (const float*)d_in[3];
    const float* bt = (const float*)d_in[4];
    const float* mu = (const float*)d_in[5];
    const float* vr = (const float*)d_in[6];
    const float* W2 = (const float*)d_in[7];
    const float* b2 = (const float*)d_in[8];
    const float* W3 = (const float*)d_in[9];
    const float* b3 = (const float*)d_in[10];
    const float* cb = (const float*)d_in[11];

    float* norms = (float*)d_ws;                       // 4096 floats (16 KB)
    float* Z     = (float*)((char*)d_ws + 16384);      // 65536 x 64 (16 MB)
    int*   out   = (int*)d_out;

    const int B = in_sizes[0] / IN_DIM;                // 65536

    k_norms<<<K_CODES / 256, 256, 0, stream>>>(cb, norms);
    k_encoder<<<B / 32, 256, 0, stream>>>(x, W1, b1, gm, bt, mu, vr, W2, b2, W3, b3, Z);
    k_argmin<<<B / 64, 256, 0, stream>>>(Z, cb, norms, out);
}

// Round 3
// 1634.739 us; speedup vs baseline: 2.5154x; 1.7944x over previous
//
#include <hip/hip_runtime.h>

// Problem constants (fixed by reference)
#define IN_DIM  256
#define HID_DIM 256
#define H2_DIM  128
#define EMB_DIM 64
#define K_CODES 4096
#define EPS_BN  1e-5f

// NOTE (R3): __launch_bounds__ second arg sets amdgpu-waves-per-eu=[N,8]; the
// backend then *targets high occupancy in that range*, clamping VGPRs (R1: 128,
// R2: 84) and spilling the micro-tile to scratch -> 7+ GB of fake HBM traffic.
// Plain __launch_bounds__(256) only caps threads (VGPR budget 256, no
// waves-per-eu attribute) -> allocator keeps the live set in registers.

// ---------------------------------------------------------------------------
// Kernel 0: half squared norms of codebook rows: norms[c] = 0.5*||e_c||^2
// ---------------------------------------------------------------------------
__global__ __launch_bounds__(256) void k_norms(const float* __restrict__ cb,
                                               float* __restrict__ norms) {
    int c = blockIdx.x * 256 + threadIdx.x;  // exactly 4096 threads
    const float4* row = reinterpret_cast<const float4*>(cb + (size_t)c * EMB_DIM);
    float s = 0.f;
#pragma unroll
    for (int i = 0; i < EMB_DIM / 4; ++i) {
        float4 v = row[i];
        s += v.x * v.x + v.y * v.y + v.z * v.z + v.w * v.w;
    }
    norms[c] = 0.5f * s;
}

// ---------------------------------------------------------------------------
// Generic global->LDS tile copy, float4 granularity, 256 threads.
// M rows x Kc cols, global row stride LDG, LDS row stride LDL (%4==0).
// ---------------------------------------------------------------------------
template <int M, int Kc, int LDG, int LDL>
__device__ __forceinline__ void g2l(const float* __restrict__ src, float* dst, int tid) {
    constexpr int NF4 = M * Kc / 4;
    constexpr int K4  = Kc / 4;
    static_assert(NF4 % 256 == 0, "tile not divisible");
#pragma unroll
    for (int it = 0; it < NF4 / 256; ++it) {
        int i   = it * 256 + tid;
        int row = i / K4;
        int c4  = i % K4;
        float4 v = *reinterpret_cast<const float4*>(src + row * LDG + c4 * 4);
        *reinterpret_cast<float4*>(dst + row * LDL + c4 * 4) = v;
    }
}

// ---------------------------------------------------------------------------
// Kernel 1: fused encoder. 32 rows per block, 256 threads, micro-tile 4x8.
//   h1 = relu(BN(x@W1^T + b1)); h2 = relu(h1@W2^T + b2); z = tanh(h2@W3^T + b3)
// rg = tid&7 (8 row-groups; rows r = ir*8+rg, ir<4), cg = tid>>3 (32 col-grps).
// LDS strides 36/260/132: all ==4 mod 32 floats -> conflict-free b128 reads.
// LDS union 51.7 KB -> 3 blocks/CU (LDS-limited occupancy).
// ---------------------------------------------------------------------------
__global__ __launch_bounds__(256) void k_encoder(
    const float* __restrict__ x,  const float* __restrict__ W1, const float* __restrict__ b1,
    const float* __restrict__ gm, const float* __restrict__ bt,
    const float* __restrict__ mu, const float* __restrict__ vr,
    const float* __restrict__ W2, const float* __restrict__ b2,
    const float* __restrict__ W3, const float* __restrict__ b3,
    float* __restrict__ Z) {
    __shared__ __align__(16) float lds[12928];  // 51.7 KB union
    const int tid = threadIdx.x;
    const int rg  = tid & 7;
    const int cg  = tid >> 3;
    const int r0  = blockIdx.x * 32;

    // ---------------- Stage 1: h1 = x @ W1^T  (k = 256, chunks of 32) -------
    float acc1[4][8];
#pragma unroll
    for (int a = 0; a < 4; ++a)
#pragma unroll
        for (int b = 0; b < 8; ++b) acc1[a][b] = 0.f;

    float* xbuf  = lds;          // [32][36]
    float* w1buf = lds + 1152;   // [256][36]

    for (int kc = 0; kc < 8; ++kc) {
        __syncthreads();
        g2l<32, 32, IN_DIM, 36>(x + (size_t)r0 * IN_DIM + kc * 32, xbuf, tid);
        g2l<256, 32, IN_DIM, 36>(W1 + kc * 32, w1buf, tid);
        __syncthreads();
#pragma unroll
        for (int k4 = 0; k4 < 8; ++k4) {
            float4 xf[4], wf[8];
#pragma unroll
            for (int ir = 0; ir < 4; ++ir)
                xf[ir] = *reinterpret_cast<float4*>(xbuf + (ir * 8 + rg) * 36 + k4 * 4);
#pragma unroll
            for (int ij = 0; ij < 8; ++ij)
                wf[ij] = *reinterpret_cast<float4*>(w1buf + (ij * 32 + cg) * 36 + k4 * 4);
#pragma unroll
            for (int ir = 0; ir < 4; ++ir)
#pragma unroll
                for (int ij = 0; ij < 8; ++ij)
                    acc1[ir][ij] += xf[ir].x * wf[ij].x + xf[ir].y * wf[ij].y +
                                    xf[ir].z * wf[ij].z + xf[ir].w * wf[ij].w;
        }
    }

    // BN (eval stats) + ReLU in registers (in place), then park h1 in LDS.
#pragma unroll
    for (int ij = 0; ij < 8; ++ij) {
        int j = ij * 32 + cg;
        float sc = gm[j] / sqrtf(vr[j] + EPS_BN);
        float sh = (b1[j] - mu[j]) * sc + bt[j];
#pragma unroll
        for (int ir = 0; ir < 4; ++ir) {
            float v = acc1[ir][ij] * sc + sh;
            acc1[ir][ij] = v > 0.f ? v : 0.f;
        }
    }

    __syncthreads();  // all stage-1 LDS reads done before overwrite
    float* h1buf = lds;          // [32][260], resident through stage 2
    float* w2buf = lds + 8320;   // [128][36]
#pragma unroll
    for (int ij = 0; ij < 8; ++ij)
#pragma unroll
        for (int ir = 0; ir < 4; ++ir)
            h1buf[(ir * 8 + rg) * 260 + ij * 32 + cg] = acc1[ir][ij];

    // ---------------- Stage 2: h2 = h1 @ W2^T (k = 256, chunks of 32) -------
    float acc2[4][4];
#pragma unroll
    for (int a = 0; a < 4; ++a)
#pragma unroll
        for (int b = 0; b < 4; ++b) acc2[a][b] = 0.f;

    for (int kc = 0; kc < 8; ++kc) {
        __syncthreads();  // first iter: h1 writes visible; later: w2buf reads done
        g2l<128, 32, HID_DIM, 36>(W2 + kc * 32, w2buf, tid);
        __syncthreads();
#pragma unroll
        for (int k4 = 0; k4 < 8; ++k4) {
            float4 hf[4], wf[4];
#pragma unroll
            for (int ir = 0; ir < 4; ++ir)
                hf[ir] = *reinterpret_cast<float4*>(h1buf + (ir * 8 + rg) * 260 + kc * 32 + k4 * 4);
#pragma unroll
            for (int ij = 0; ij < 4; ++ij)
                wf[ij] = *reinterpret_cast<float4*>(w2buf + (ij * 32 + cg) * 36 + k4 * 4);
#pragma unroll
            for (int ir = 0; ir < 4; ++ir)
#pragma unroll
                for (int ij = 0; ij < 4; ++ij)
                    acc2[ir][ij] += hf[ir].x * wf[ij].x + hf[ir].y * wf[ij].y +
                                    hf[ir].z * wf[ij].z + hf[ir].w * wf[ij].w;
        }
    }

    // ReLU(+b2) -> LDS, stage W3, compute stage 3.
    __syncthreads();  // all stage-2 reads of h1buf/w2buf done
    float* h2buf = lds;          // [32][132]
    float* w3buf = lds + 4224;   // [64][132]
#pragma unroll
    for (int ij = 0; ij < 4; ++ij) {
        int j2 = ij * 32 + cg;
        float bias = b2[j2];
#pragma unroll
        for (int ir = 0; ir < 4; ++ir) {
            float v = acc2[ir][ij] + bias;
            h2buf[(ir * 8 + rg) * 132 + j2] = v > 0.f ? v : 0.f;
        }
    }
    g2l<64, 128, H2_DIM, 132>(W3, w3buf, tid);
    __syncthreads();

    // ---------------- Stage 3: z = tanh(h2 @ W3^T + b3) (k = 128) -----------
    float acc3[4][2];
#pragma unroll
    for (int a = 0; a < 4; ++a) { acc3[a][0] = 0.f; acc3[a][1] = 0.f; }
#pragma unroll
    for (int k4 = 0; k4 < 32; ++k4) {
        float4 hf[4], wf[2];
#pragma unroll
        for (int ir = 0; ir < 4; ++ir)
            hf[ir] = *reinterpret_cast<float4*>(h2buf + (ir * 8 + rg) * 132 + k4 * 4);
#pragma unroll
        for (int ij = 0; ij < 2; ++ij)
            wf[ij] = *reinterpret_cast<float4*>(w3buf + (ij * 32 + cg) * 132 + k4 * 4);
#pragma unroll
        for (int ir = 0; ir < 4; ++ir)
#pragma unroll
            for (int ij = 0; ij < 2; ++ij)
                acc3[ir][ij] += hf[ir].x * wf[ij].x + hf[ir].y * wf[ij].y +
                                hf[ir].z * wf[ij].z + hf[ir].w * wf[ij].w;
    }
#pragma unroll
    for (int ij = 0; ij < 2; ++ij) {
        int j3 = ij * 32 + cg;
        float bias = b3[j3];
#pragma unroll
        for (int ir = 0; ir < 4; ++ir) {
            float zv = tanhf(acc3[ir][ij] + bias);
            Z[(size_t)(r0 + ir * 8 + rg) * EMB_DIM + j3] = zv;
        }
    }
}

// ---------------------------------------------------------------------------
// Kernel 2: nearest-code argmin. 64 rows/block, 128-code chunks.
// score(r,c) = 0.5*||e_c||^2 - z_r . e_c   (||z||^2 dropped: row-constant)
// ---------------------------------------------------------------------------
__global__ __launch_bounds__(256) void k_argmin(
    const float* __restrict__ Z, const float* __restrict__ cb,
    const float* __restrict__ norms, int* __restrict__ out) {
    __shared__ __align__(16) float lds[13184];  // 52.7 KB
    float* zbuf = lds;           // [64][68]
    float* ebuf = lds + 4352;    // [128][68]
    float* nbuf = lds + 13056;   // [128]
    const int tid = threadIdx.x;
    const int rg  = tid & 7;
    const int cg  = tid >> 3;
    const int r0  = blockIdx.x * 64;

    g2l<64, 64, EMB_DIM, 68>(Z + (size_t)r0 * EMB_DIM, zbuf, tid);

    float bv[8];
    int   bi[8];
#pragma unroll
    for (int ir = 0; ir < 8; ++ir) { bv[ir] = 3.4e38f; bi[ir] = 0; }

    for (int ch = 0; ch < K_CODES / 128; ++ch) {
        __syncthreads();
        g2l<128, 64, EMB_DIM, 68>(cb + (size_t)ch * 128 * EMB_DIM, ebuf, tid);
        if (tid < 128) nbuf[tid] = norms[ch * 128 + tid];
        __syncthreads();

        float acc[8][4];
#pragma unroll
        for (int a = 0; a < 8; ++a)
#pragma unroll
            for (int b = 0; b < 4; ++b) acc[a][b] = 0.f;

#pragma unroll
        for (int k4 = 0; k4 < 16; ++k4) {
            float4 zf[8], ef[4];
#pragma unroll
            for (int ir = 0; ir < 8; ++ir)
                zf[ir] = *reinterpret_cast<float4*>(zbuf + (ir * 8 + rg) * 68 + k4 * 4);
#pragma unroll
            for (int ic = 0; ic < 4; ++ic)
                ef[ic] = *reinterpret_cast<float4*>(ebuf + (ic * 32 + cg) * 68 + k4 * 4);
#pragma unroll
            for (int ir = 0; ir < 8; ++ir)
#pragma unroll
                for (int ic = 0; ic < 4; ++ic)
                    acc[ir][ic] += zf[ir].x * ef[ic].x + zf[ir].y * ef[ic].y +
                                   zf[ir].z * ef[ic].z + zf[ir].w * ef[ic].w;
        }

#pragma unroll
        for (int ic = 0; ic < 4; ++ic) {
            int cl = ic * 32 + cg;
            float nh = nbuf[cl];
            int cglob = ch * 128 + cl;
#pragma unroll
            for (int ir = 0; ir < 8; ++ir) {
                float s = nh - acc[ir][ic];
                bool lt = s < bv[ir];
                bv[ir] = lt ? s : bv[ir];
                bi[ir] = lt ? cglob : bi[ir];
            }
        }
    }

    // Cross-thread (cg) reduction through LDS; stride 33 -> conflict-free scan.
    __syncthreads();
    float* redv = lds;                                  // [64][33]
    int*   redi = reinterpret_cast<int*>(lds + 2112);   // [64][33]
#pragma unroll
    for (int ir = 0; ir < 8; ++ir) {
        int r = ir * 8 + rg;
        redv[r * 33 + cg] = bv[ir];
        redi[r * 33 + cg] = bi[ir];
    }
    __syncthreads();
    if (tid < 64) {
        float v  = redv[tid * 33];
        int   ix = redi[tid * 33];
#pragma unroll
        for (int j = 1; j < 32; ++j) {
            float vj = redv[tid * 33 + j];
            int   ij = redi[tid * 33 + j];
            if (vj < v) { v = vj; ix = ij; }
        }
        out[r0 + tid] = ix;
    }
}

// ---------------------------------------------------------------------------
extern "C" void kernel_launch(void* const* d_in, const int* in_sizes, int n_in,
                              void* d_out, int out_size, void* d_ws, size_t ws_size,
                              hipStream_t stream) {
    (void)n_in; (void)out_size; (void)ws_size;
    const float* x  = (const float*)d_in[0];
    const float* W1 = (const float*)d_in[1];
    const float* b1 = (const float*)d_in[2];
    const float* gm = (const float*)d_in[3];
    const float* bt = (const float*)d_in[4];
    const float* mu = (const float*)d_in[5];
    const float* vr = (const float*)d_in[6];
    const float* W2 = (const float*)d_in[7];
    const float* b2 = (const float*)d_in[8];
    const float* W3 = (const float*)d_in[9];
    const float* b3 = (const float*)d_in[10];
    const float* cb = (const float*)d_in[11];

    float* norms = (float*)d_ws;                       // 4096 floats (16 KB)
    float* Z     = (float*)((char*)d_ws + 16384);      // 65536 x 64 (16 MB)
    int*   out   = (int*)d_out;

    const int B = in_sizes[0] / IN_DIM;                // 65536

    k_norms<<<K_CODES / 256, 256, 0, stream>>>(cb, norms);
    k_encoder<<<B / 32, 256, 0, stream>>>(x, W1, b1, gm, bt, mu, vr, W2, b2, W3, b3, Z);
    k_argmin<<<B / 64, 256, 0, stream>>>(Z, cb, norms, out);
}

// Round 4
// 846.389 us; speedup vs baseline: 4.8583x; 1.9314x over previous
//
#include <hip/hip_runtime.h>

// Problem constants (fixed by reference)
#define IN_DIM  256
#define HID_DIM 256
#define H2_DIM  128
#define EMB_DIM 64
#define K_CODES 4096
#define EPS_BN  1e-5f

// R3 lesson: __launch_bounds__(256,N) forces a VGPR clamp (spill). R4 lesson
// candidate: full unroll of the k4 loops lets the scheduler hoist ~96 b128
// loads -> ~300+ live regs -> spill even at the 256 cap (WRITE_SIZE 692 MB vs
// 16 MB real). Fix: #pragma unroll 2 on the fragment loops — 2 iterations of
// fragments in flight (~96 regs incl. acc), loop-carried acc stops hoisting.

// ---------------------------------------------------------------------------
// Kernel 0: half squared norms of codebook rows: norms[c] = 0.5*||e_c||^2
// ---------------------------------------------------------------------------
__global__ __launch_bounds__(256) void k_norms(const float* __restrict__ cb,
                                               float* __restrict__ norms) {
    int c = blockIdx.x * 256 + threadIdx.x;  // exactly 4096 threads
    const float4* row = reinterpret_cast<const float4*>(cb + (size_t)c * EMB_DIM);
    float s = 0.f;
#pragma unroll
    for (int i = 0; i < EMB_DIM / 4; ++i) {
        float4 v = row[i];
        s += v.x * v.x + v.y * v.y + v.z * v.z + v.w * v.w;
    }
    norms[c] = 0.5f * s;
}

// ---------------------------------------------------------------------------
// Generic global->LDS tile copy, float4 granularity, 256 threads.
// ---------------------------------------------------------------------------
template <int M, int Kc, int LDG, int LDL>
__device__ __forceinline__ void g2l(const float* __restrict__ src, float* dst, int tid) {
    constexpr int NF4 = M * Kc / 4;
    constexpr int K4  = Kc / 4;
    static_assert(NF4 % 256 == 0, "tile not divisible");
#pragma unroll
    for (int it = 0; it < NF4 / 256; ++it) {
        int i   = it * 256 + tid;
        int row = i / K4;
        int c4  = i % K4;
        float4 v = *reinterpret_cast<const float4*>(src + row * LDG + c4 * 4);
        *reinterpret_cast<float4*>(dst + row * LDL + c4 * 4) = v;
    }
}

// ---------------------------------------------------------------------------
// Kernel 1: fused encoder. 32 rows per block, 256 threads, micro-tile 4x8.
// ---------------------------------------------------------------------------
__global__ __launch_bounds__(256) void k_encoder(
    const float* __restrict__ x,  const float* __restrict__ W1, const float* __restrict__ b1,
    const float* __restrict__ gm, const float* __restrict__ bt,
    const float* __restrict__ mu, const float* __restrict__ vr,
    const float* __restrict__ W2, const float* __restrict__ b2,
    const float* __restrict__ W3, const float* __restrict__ b3,
    float* __restrict__ Z) {
    __shared__ __align__(16) float lds[12928];  // 51.7 KB union
    const int tid = threadIdx.x;
    const int rg  = tid & 7;
    const int cg  = tid >> 3;
    const int r0  = blockIdx.x * 32;

    // ---------------- Stage 1: h1 = x @ W1^T  (k = 256, chunks of 32) -------
    float acc1[4][8];
#pragma unroll
    for (int a = 0; a < 4; ++a)
#pragma unroll
        for (int b = 0; b < 8; ++b) acc1[a][b] = 0.f;

    float* xbuf  = lds;          // [32][36]
    float* w1buf = lds + 1152;   // [256][36]

    for (int kc = 0; kc < 8; ++kc) {
        __syncthreads();
        g2l<32, 32, IN_DIM, 36>(x + (size_t)r0 * IN_DIM + kc * 32, xbuf, tid);
        g2l<256, 32, IN_DIM, 36>(W1 + kc * 32, w1buf, tid);
        __syncthreads();
#pragma unroll 2
        for (int k4 = 0; k4 < 8; ++k4) {
            float4 xf[4], wf[8];
#pragma unroll
            for (int ir = 0; ir < 4; ++ir)
                xf[ir] = *reinterpret_cast<float4*>(xbuf + (ir * 8 + rg) * 36 + k4 * 4);
#pragma unroll
            for (int ij = 0; ij < 8; ++ij)
                wf[ij] = *reinterpret_cast<float4*>(w1buf + (ij * 32 + cg) * 36 + k4 * 4);
#pragma unroll
            for (int ir = 0; ir < 4; ++ir)
#pragma unroll
                for (int ij = 0; ij < 8; ++ij)
                    acc1[ir][ij] += xf[ir].x * wf[ij].x + xf[ir].y * wf[ij].y +
                                    xf[ir].z * wf[ij].z + xf[ir].w * wf[ij].w;
        }
    }

    // BN (eval stats) + ReLU in registers (in place), then park h1 in LDS.
#pragma unroll
    for (int ij = 0; ij < 8; ++ij) {
        int j = ij * 32 + cg;
        float sc = gm[j] / sqrtf(vr[j] + EPS_BN);
        float sh = (b1[j] - mu[j]) * sc + bt[j];
#pragma unroll
        for (int ir = 0; ir < 4; ++ir) {
            float v = acc1[ir][ij] * sc + sh;
            acc1[ir][ij] = v > 0.f ? v : 0.f;
        }
    }

    __syncthreads();  // all stage-1 LDS reads done before overwrite
    float* h1buf = lds;          // [32][260], resident through stage 2
    float* w2buf = lds + 8320;   // [128][36]
#pragma unroll
    for (int ij = 0; ij < 8; ++ij)
#pragma unroll
        for (int ir = 0; ir < 4; ++ir)
            h1buf[(ir * 8 + rg) * 260 + ij * 32 + cg] = acc1[ir][ij];

    // ---------------- Stage 2: h2 = h1 @ W2^T (k = 256, chunks of 32) -------
    float acc2[4][4];
#pragma unroll
    for (int a = 0; a < 4; ++a)
#pragma unroll
        for (int b = 0; b < 4; ++b) acc2[a][b] = 0.f;

    for (int kc = 0; kc < 8; ++kc) {
        __syncthreads();  // first iter: h1 writes visible; later: w2buf reads done
        g2l<128, 32, HID_DIM, 36>(W2 + kc * 32, w2buf, tid);
        __syncthreads();
#pragma unroll 2
        for (int k4 = 0; k4 < 8; ++k4) {
            float4 hf[4], wf[4];
#pragma unroll
            for (int ir = 0; ir < 4; ++ir)
                hf[ir] = *reinterpret_cast<float4*>(h1buf + (ir * 8 + rg) * 260 + kc * 32 + k4 * 4);
#pragma unroll
            for (int ij = 0; ij < 4; ++ij)
                wf[ij] = *reinterpret_cast<float4*>(w2buf + (ij * 32 + cg) * 36 + k4 * 4);
#pragma unroll
            for (int ir = 0; ir < 4; ++ir)
#pragma unroll
                for (int ij = 0; ij < 4; ++ij)
                    acc2[ir][ij] += hf[ir].x * wf[ij].x + hf[ir].y * wf[ij].y +
                                    hf[ir].z * wf[ij].z + hf[ir].w * wf[ij].w;
        }
    }

    // ReLU(+b2) -> LDS, stage W3, compute stage 3.
    __syncthreads();  // all stage-2 reads of h1buf/w2buf done
    float* h2buf = lds;          // [32][132]
    float* w3buf = lds + 4224;   // [64][132]
#pragma unroll
    for (int ij = 0; ij < 4; ++ij) {
        int j2 = ij * 32 + cg;
        float bias = b2[j2];
#pragma unroll
        for (int ir = 0; ir < 4; ++ir) {
            float v = acc2[ir][ij] + bias;
            h2buf[(ir * 8 + rg) * 132 + j2] = v > 0.f ? v : 0.f;
        }
    }
    g2l<64, 128, H2_DIM, 132>(W3, w3buf, tid);
    __syncthreads();

    // ---------------- Stage 3: z = tanh(h2 @ W3^T + b3) (k = 128) -----------
    float acc3[4][2];
#pragma unroll
    for (int a = 0; a < 4; ++a) { acc3[a][0] = 0.f; acc3[a][1] = 0.f; }
#pragma unroll 2
    for (int k4 = 0; k4 < 32; ++k4) {
        float4 hf[4], wf[2];
#pragma unroll
        for (int ir = 0; ir < 4; ++ir)
            hf[ir] = *reinterpret_cast<float4*>(h2buf + (ir * 8 + rg) * 132 + k4 * 4);
#pragma unroll
        for (int ij = 0; ij < 2; ++ij)
            wf[ij] = *reinterpret_cast<float4*>(w3buf + (ij * 32 + cg) * 132 + k4 * 4);
#pragma unroll
        for (int ir = 0; ir < 4; ++ir)
#pragma unroll
            for (int ij = 0; ij < 2; ++ij)
                acc3[ir][ij] += hf[ir].x * wf[ij].x + hf[ir].y * wf[ij].y +
                                hf[ir].z * wf[ij].z + hf[ir].w * wf[ij].w;
    }
#pragma unroll
    for (int ij = 0; ij < 2; ++ij) {
        int j3 = ij * 32 + cg;
        float bias = b3[j3];
#pragma unroll
        for (int ir = 0; ir < 4; ++ir) {
            float zv = tanhf(acc3[ir][ij] + bias);
            Z[(size_t)(r0 + ir * 8 + rg) * EMB_DIM + j3] = zv;
        }
    }
}

// ---------------------------------------------------------------------------
// Kernel 2: nearest-code argmin. 64 rows/block, 128-code chunks.
// score(r,c) = 0.5*||e_c||^2 - z_r . e_c   (||z||^2 dropped: row-constant)
// ---------------------------------------------------------------------------
__global__ __launch_bounds__(256) void k_argmin(
    const float* __restrict__ Z, const float* __restrict__ cb,
    const float* __restrict__ norms, int* __restrict__ out) {
    __shared__ __align__(16) float lds[13184];  // 52.7 KB
    float* zbuf = lds;           // [64][68]
    float* ebuf = lds + 4352;    // [128][68]
    float* nbuf = lds + 13056;   // [128]
    const int tid = threadIdx.x;
    const int rg  = tid & 7;
    const int cg  = tid >> 3;
    const int r0  = blockIdx.x * 64;

    g2l<64, 64, EMB_DIM, 68>(Z + (size_t)r0 * EMB_DIM, zbuf, tid);

    float bv[8];
    int   bi[8];
#pragma unroll
    for (int ir = 0; ir < 8; ++ir) { bv[ir] = 3.4e38f; bi[ir] = 0; }

    for (int ch = 0; ch < K_CODES / 128; ++ch) {
        __syncthreads();
        g2l<128, 64, EMB_DIM, 68>(cb + (size_t)ch * 128 * EMB_DIM, ebuf, tid);
        if (tid < 128) nbuf[tid] = norms[ch * 128 + tid];
        __syncthreads();

        float acc[8][4];
#pragma unroll
        for (int a = 0; a < 8; ++a)
#pragma unroll
            for (int b = 0; b < 4; ++b) acc[a][b] = 0.f;

#pragma unroll 2
        for (int k4 = 0; k4 < 16; ++k4) {
            float4 zf[8], ef[4];
#pragma unroll
            for (int ir = 0; ir < 8; ++ir)
                zf[ir] = *reinterpret_cast<float4*>(zbuf + (ir * 8 + rg) * 68 + k4 * 4);
#pragma unroll
            for (int ic = 0; ic < 4; ++ic)
                ef[ic] = *reinterpret_cast<float4*>(ebuf + (ic * 32 + cg) * 68 + k4 * 4);
#pragma unroll
            for (int ir = 0; ir < 8; ++ir)
#pragma unroll
                for (int ic = 0; ic < 4; ++ic)
                    acc[ir][ic] += zf[ir].x * ef[ic].x + zf[ir].y * ef[ic].y +
                                   zf[ir].z * ef[ic].z + zf[ir].w * ef[ic].w;
        }

#pragma unroll
        for (int ic = 0; ic < 4; ++ic) {
            int cl = ic * 32 + cg;
            float nh = nbuf[cl];
            int cglob = ch * 128 + cl;
#pragma unroll
            for (int ir = 0; ir < 8; ++ir) {
                float s = nh - acc[ir][ic];
                bool lt = s < bv[ir];
                bv[ir] = lt ? s : bv[ir];
                bi[ir] = lt ? cglob : bi[ir];
            }
        }
    }

    // Cross-thread (cg) reduction through LDS; stride 33 -> conflict-free scan.
    __syncthreads();
    float* redv = lds;                                  // [64][33]
    int*   redi = reinterpret_cast<int*>(lds + 2112);   // [64][33]
#pragma unroll
    for (int ir = 0; ir < 8; ++ir) {
        int r = ir * 8 + rg;
        redv[r * 33 + cg] = bv[ir];
        redi[r * 33 + cg] = bi[ir];
    }
    __syncthreads();
    if (tid < 64) {
        float v  = redv[tid * 33];
        int   ix = redi[tid * 33];
#pragma unroll
        for (int j = 1; j < 32; ++j) {
            float vj = redv[tid * 33 + j];
            int   ij = redi[tid * 33 + j];
            if (vj < v) { v = vj; ix = ij; }
        }
        out[r0 + tid] = ix;
    }
}

// ---------------------------------------------------------------------------
extern "C" void kernel_launch(void* const* d_in, const int* in_sizes, int n_in,
                              void* d_out, int out_size, void* d_ws, size_t ws_size,
                              hipStream_t stream) {
    (void)n_in; (void)out_size; (void)ws_size;
    const float* x  = (const float*)d_in[0];
    const float* W1 = (const float*)d_in[1];
    const float* b1 = (const float*)d_in[2];
    const float* gm = (const float*)d_in[3];
    const float* bt = (const float*)d_in[4];
    const float* mu = (const float*)d_in[5];
    const float* vr = (const float*)d_in[6];
    const float* W2 = (const float*)d_in[7];
    const float* b2 = (const float*)d_in[8];
    const float* W3 = (const float*)d_in[9];
    const float* b3 = (const float*)d_in[10];
    const float* cb = (const float*)d_in[11];

    float* norms = (float*)d_ws;                       // 4096 floats (16 KB)
    float* Z     = (float*)((char*)d_ws + 16384);      // 65536 x 64 (16 MB)
    int*   out   = (int*)d_out;

    const int B = in_sizes[0] / IN_DIM;                // 65536

    k_norms<<<K_CODES / 256, 256, 0, stream>>>(cb, norms);
    k_encoder<<<B / 32, 256, 0, stream>>>(x, W1, b1, gm, bt, mu, vr, W2, b2, W3, b3, Z);
    k_argmin<<<B / 64, 256, 0, stream>>>(Z, cb, norms, out);
}

// Round 5
// 473.733 us; speedup vs baseline: 8.6800x; 1.7866x over previous
//
#include <hip/hip_runtime.h>

// Problem constants (fixed by reference)
#define IN_DIM  256
#define HID_DIM 256
#define H2_DIM  128
#define EMB_DIM 64
#define K_CODES 4096
#define EPS_BN  1e-5f

// R3: __launch_bounds__(256,N) VGPR-clamps -> spill. R4: full unroll of
// fragment loops -> scheduler hoists ~96 b128 loads -> spill at 256 cap;
// #pragma unroll 2 fixed it (hbm_bytes 1.3GB->13MB). R5: argmin is an fp32
// VALU wall (57 TF of ~103) -> move the distance GEMM to the matrix pipe via
// two-term fp16 split (z=zh+zl, e=eh+el; dot ~ zh.eh + zl.eh + zh.el, error
// ~1.5e-6 ~ fp32 reorder noise). Norms stay fp32 in the epilogue.

typedef _Float16 f16;
typedef _Float16 f16x8 __attribute__((ext_vector_type(8)));
typedef float    f32x16 __attribute__((ext_vector_type(16)));

// ---------------------------------------------------------------------------
// Kernel 0a: half squared norms of codebook rows: norms[c] = 0.5*||e_c||^2
// ---------------------------------------------------------------------------
__global__ __launch_bounds__(256) void k_norms(const float* __restrict__ cb,
                                               float* __restrict__ norms) {
    int c = blockIdx.x * 256 + threadIdx.x;  // exactly 4096 threads
    const float4* row = reinterpret_cast<const float4*>(cb + (size_t)c * EMB_DIM);
    float s = 0.f;
#pragma unroll
    for (int i = 0; i < EMB_DIM / 4; ++i) {
        float4 v = row[i];
        s += v.x * v.x + v.y * v.y + v.z * v.z + v.w * v.w;
    }
    norms[c] = 0.5f * s;
}

// ---------------------------------------------------------------------------
// Kernel 0b: split codebook into fp16 hi/lo planes (residual <= 2^-22 |e|).
// ---------------------------------------------------------------------------
__global__ __launch_bounds__(256) void k_cvt(const float* __restrict__ cb,
                                             f16* __restrict__ cbh,
                                             f16* __restrict__ cbl) {
    int i = blockIdx.x * 256 + threadIdx.x;  // K_CODES*EMB_DIM threads
    float v = cb[i];
    f16 h = (f16)v;
    cbh[i] = h;
    cbl[i] = (f16)(v - (float)h);  // v-h exact in fp32 (Sterbenz)
}

// ---------------------------------------------------------------------------
// Generic global->LDS tile copy, float4 granularity, 256 threads (fp32).
// ---------------------------------------------------------------------------
template <int M, int Kc, int LDG, int LDL>
__device__ __forceinline__ void g2l(const float* __restrict__ src, float* dst, int tid) {
    constexpr int NF4 = M * Kc / 4;
    constexpr int K4  = Kc / 4;
    static_assert(NF4 % 256 == 0, "tile not divisible");
#pragma unroll
    for (int it = 0; it < NF4 / 256; ++it) {
        int i   = it * 256 + tid;
        int row = i / K4;
        int c4  = i % K4;
        float4 v = *reinterpret_cast<const float4*>(src + row * LDG + c4 * 4);
        *reinterpret_cast<float4*>(dst + row * LDL + c4 * 4) = v;
    }
}

// ---------------------------------------------------------------------------
// Kernel 1: fused encoder. 32 rows per block, 256 threads, micro-tile 4x8.
// Epilogue now emits z as fp16 hi/lo planes for the MFMA argmin.
// ---------------------------------------------------------------------------
__global__ __launch_bounds__(256) void k_encoder(
    const float* __restrict__ x,  const float* __restrict__ W1, const float* __restrict__ b1,
    const float* __restrict__ gm, const float* __restrict__ bt,
    const float* __restrict__ mu, const float* __restrict__ vr,
    const float* __restrict__ W2, const float* __restrict__ b2,
    const float* __restrict__ W3, const float* __restrict__ b3,
    f16* __restrict__ Zh, f16* __restrict__ Zl) {
    __shared__ __align__(16) float lds[12928];  // 51.7 KB union
    const int tid = threadIdx.x;
    const int rg  = tid & 7;
    const int cg  = tid >> 3;
    const int r0  = blockIdx.x * 32;

    // ---------------- Stage 1: h1 = x @ W1^T  (k = 256, chunks of 32) -------
    float acc1[4][8];
#pragma unroll
    for (int a = 0; a < 4; ++a)
#pragma unroll
        for (int b = 0; b < 8; ++b) acc1[a][b] = 0.f;

    float* xbuf  = lds;          // [32][36]
    float* w1buf = lds + 1152;   // [256][36]

    for (int kc = 0; kc < 8; ++kc) {
        __syncthreads();
        g2l<32, 32, IN_DIM, 36>(x + (size_t)r0 * IN_DIM + kc * 32, xbuf, tid);
        g2l<256, 32, IN_DIM, 36>(W1 + kc * 32, w1buf, tid);
        __syncthreads();
#pragma unroll 2
        for (int k4 = 0; k4 < 8; ++k4) {
            float4 xf[4], wf[8];
#pragma unroll
            for (int ir = 0; ir < 4; ++ir)
                xf[ir] = *reinterpret_cast<float4*>(xbuf + (ir * 8 + rg) * 36 + k4 * 4);
#pragma unroll
            for (int ij = 0; ij < 8; ++ij)
                wf[ij] = *reinterpret_cast<float4*>(w1buf + (ij * 32 + cg) * 36 + k4 * 4);
#pragma unroll
            for (int ir = 0; ir < 4; ++ir)
#pragma unroll
                for (int ij = 0; ij < 8; ++ij)
                    acc1[ir][ij] += xf[ir].x * wf[ij].x + xf[ir].y * wf[ij].y +
                                    xf[ir].z * wf[ij].z + xf[ir].w * wf[ij].w;
        }
    }

    // BN (eval stats) + ReLU in registers (in place), then park h1 in LDS.
#pragma unroll
    for (int ij = 0; ij < 8; ++ij) {
        int j = ij * 32 + cg;
        float sc = gm[j] / sqrtf(vr[j] + EPS_BN);
        float sh = (b1[j] - mu[j]) * sc + bt[j];
#pragma unroll
        for (int ir = 0; ir < 4; ++ir) {
            float v = acc1[ir][ij] * sc + sh;
            acc1[ir][ij] = v > 0.f ? v : 0.f;
        }
    }

    __syncthreads();  // all stage-1 LDS reads done before overwrite
    float* h1buf = lds;          // [32][260], resident through stage 2
    float* w2buf = lds + 8320;   // [128][36]
#pragma unroll
    for (int ij = 0; ij < 8; ++ij)
#pragma unroll
        for (int ir = 0; ir < 4; ++ir)
            h1buf[(ir * 8 + rg) * 260 + ij * 32 + cg] = acc1[ir][ij];

    // ---------------- Stage 2: h2 = h1 @ W2^T (k = 256, chunks of 32) -------
    float acc2[4][4];
#pragma unroll
    for (int a = 0; a < 4; ++a)
#pragma unroll
        for (int b = 0; b < 4; ++b) acc2[a][b] = 0.f;

    for (int kc = 0; kc < 8; ++kc) {
        __syncthreads();
        g2l<128, 32, HID_DIM, 36>(W2 + kc * 32, w2buf, tid);
        __syncthreads();
#pragma unroll 2
        for (int k4 = 0; k4 < 8; ++k4) {
            float4 hf[4], wf[4];
#pragma unroll
            for (int ir = 0; ir < 4; ++ir)
                hf[ir] = *reinterpret_cast<float4*>(h1buf + (ir * 8 + rg) * 260 + kc * 32 + k4 * 4);
#pragma unroll
            for (int ij = 0; ij < 4; ++ij)
                wf[ij] = *reinterpret_cast<float4*>(w2buf + (ij * 32 + cg) * 36 + k4 * 4);
#pragma unroll
            for (int ir = 0; ir < 4; ++ir)
#pragma unroll
                for (int ij = 0; ij < 4; ++ij)
                    acc2[ir][ij] += hf[ir].x * wf[ij].x + hf[ir].y * wf[ij].y +
                                    hf[ir].z * wf[ij].z + hf[ir].w * wf[ij].w;
        }
    }

    // ReLU(+b2) -> LDS, stage W3, compute stage 3.
    __syncthreads();
    float* h2buf = lds;          // [32][132]
    float* w3buf = lds + 4224;   // [64][132]
#pragma unroll
    for (int ij = 0; ij < 4; ++ij) {
        int j2 = ij * 32 + cg;
        float bias = b2[j2];
#pragma unroll
        for (int ir = 0; ir < 4; ++ir) {
            float v = acc2[ir][ij] + bias;
            h2buf[(ir * 8 + rg) * 132 + j2] = v > 0.f ? v : 0.f;
        }
    }
    g2l<64, 128, H2_DIM, 132>(W3, w3buf, tid);
    __syncthreads();

    // ---------------- Stage 3: z = tanh(h2 @ W3^T + b3) (k = 128) -----------
    float acc3[4][2];
#pragma unroll
    for (int a = 0; a < 4; ++a) { acc3[a][0] = 0.f; acc3[a][1] = 0.f; }
#pragma unroll 2
    for (int k4 = 0; k4 < 32; ++k4) {
        float4 hf[4], wf[2];
#pragma unroll
        for (int ir = 0; ir < 4; ++ir)
            hf[ir] = *reinterpret_cast<float4*>(h2buf + (ir * 8 + rg) * 132 + k4 * 4);
#pragma unroll
        for (int ij = 0; ij < 2; ++ij)
            wf[ij] = *reinterpret_cast<float4*>(w3buf + (ij * 32 + cg) * 132 + k4 * 4);
#pragma unroll
        for (int ir = 0; ir < 4; ++ir)
#pragma unroll
            for (int ij = 0; ij < 2; ++ij)
                acc3[ir][ij] += hf[ir].x * wf[ij].x + hf[ir].y * wf[ij].y +
                                hf[ir].z * wf[ij].z + hf[ir].w * wf[ij].w;
    }
#pragma unroll
    for (int ij = 0; ij < 2; ++ij) {
        int j3 = ij * 32 + cg;
        float bias = b3[j3];
#pragma unroll
        for (int ir = 0; ir < 4; ++ir) {
            float zv = tanhf(acc3[ir][ij] + bias);
            size_t idx = (size_t)(r0 + ir * 8 + rg) * EMB_DIM + j3;
            f16 h = (f16)zv;
            Zh[idx] = h;
            Zl[idx] = (f16)(zv - (float)h);
        }
    }
}

// ---------------------------------------------------------------------------
// Kernel 2: MFMA argmin. 128 rows/block (4 waves x 32 rows), 128-code chunks.
// score(r,c) = z_r.e_c - 0.5||e_c||^2, maximized == argmin distance.
// v_mfma_f32_32x32x16_f16: A[m=lane&31][k=(lane>>5)*8+j]; B[k][n=lane&31]
// same k-mapping; C: col=lane&31, row=(reg&3)+8*(reg>>2)+4*(lane>>5).
// LDS row stride 72 f16 = 144 B (16B-aligned for b128; 36 banks -> 2-way max).
// ---------------------------------------------------------------------------
__global__ __launch_bounds__(256) void k_argmin_mfma(
    const f16* __restrict__ Zh, const f16* __restrict__ Zl,
    const f16* __restrict__ cbh, const f16* __restrict__ cbl,
    const float* __restrict__ norms, int* __restrict__ out) {
    __shared__ __align__(16) f16 sm[37120];  // 74.2 KB -> 2 blocks/CU
    f16* zh  = sm;            // [128][72]
    f16* zl  = sm + 9216;     // [128][72]
    f16* ebh = sm + 18432;    // [128][72]
    f16* ebl = sm + 27648;    // [128][72]
    float* nbuf = (float*)(sm + 36864);  // [128]
    const int tid  = threadIdx.x;
    const int lane = tid & 63;
    const int w    = tid >> 6;    // wave 0..3 -> rows w*32..w*32+31
    const int ln31 = lane & 31;
    const int q    = lane >> 5;
    const int r0   = blockIdx.x * 128;

    // Stage Z hi/lo rows r0..r0+127 (row = 8 float4; LDS row = 9 float4).
    {
        const float4* srch = (const float4*)(Zh + (size_t)r0 * EMB_DIM);
        const float4* srcl = (const float4*)(Zl + (size_t)r0 * EMB_DIM);
        float4* dsth = (float4*)zh;
        float4* dstl = (float4*)zl;
#pragma unroll
        for (int it = 0; it < 4; ++it) {
            int i = it * 256 + tid;
            int row = i >> 3, c8 = i & 7;
            dsth[row * 9 + c8] = srch[row * 8 + c8];
            dstl[row * 9 + c8] = srcl[row * 8 + c8];
        }
    }
    __syncthreads();

    // A fragments: loaded once, reused across all 4096 codes.
    f16x8 ah[4], al[4];
#pragma unroll
    for (int ks = 0; ks < 4; ++ks) {
        int off = (w * 32 + ln31) * 72 + ks * 16 + q * 8;
        ah[ks] = *(const f16x8*)(zh + off);
        al[ks] = *(const f16x8*)(zl + off);
    }

    float bv[16];
    int   bi[16];
#pragma unroll
    for (int i = 0; i < 16; ++i) { bv[i] = -3.4e38f; bi[i] = 0; }

    for (int ch = 0; ch < K_CODES / 128; ++ch) {
        __syncthreads();  // prior tile reads done
        const float4* srch = (const float4*)(cbh + (size_t)ch * 128 * EMB_DIM);
        const float4* srcl = (const float4*)(cbl + (size_t)ch * 128 * EMB_DIM);
        float4* dsth = (float4*)ebh;
        float4* dstl = (float4*)ebl;
#pragma unroll
        for (int it = 0; it < 4; ++it) {
            int i = it * 256 + tid;
            int row = i >> 3, c8 = i & 7;
            dsth[row * 9 + c8] = srch[row * 8 + c8];
            dstl[row * 9 + c8] = srcl[row * 8 + c8];
        }
        if (tid < 128) nbuf[tid] = norms[ch * 128 + tid];
        __syncthreads();

#pragma unroll 1
        for (int ct = 0; ct < 4; ++ct) {
            f16x8 bh[4], bl[4];
#pragma unroll
            for (int ks = 0; ks < 4; ++ks) {
                int off = (ct * 32 + ln31) * 72 + ks * 16 + q * 8;
                bh[ks] = *(const f16x8*)(ebh + off);
                bl[ks] = *(const f16x8*)(ebl + off);
            }
            f32x16 acc0 = {};
            f32x16 acc1 = {};
#pragma unroll
            for (int ks = 0; ks < 4; ks += 2) {  // two acc chains, depth-2 dep
                acc0 = __builtin_amdgcn_mfma_f32_32x32x16_f16(ah[ks],     bh[ks],     acc0, 0, 0, 0);
                acc1 = __builtin_amdgcn_mfma_f32_32x32x16_f16(ah[ks + 1], bh[ks + 1], acc1, 0, 0, 0);
                acc0 = __builtin_amdgcn_mfma_f32_32x32x16_f16(al[ks],     bh[ks],     acc0, 0, 0, 0);
                acc1 = __builtin_amdgcn_mfma_f32_32x32x16_f16(al[ks + 1], bh[ks + 1], acc1, 0, 0, 0);
                acc0 = __builtin_amdgcn_mfma_f32_32x32x16_f16(ah[ks],     bl[ks],     acc0, 0, 0, 0);
                acc1 = __builtin_amdgcn_mfma_f32_32x32x16_f16(ah[ks + 1], bl[ks + 1], acc1, 0, 0, 0);
            }
            float nv  = nbuf[ct * 32 + ln31];   // per-lane constant (col-indexed)
            int   col = ch * 128 + ct * 32 + ln31;
#pragma unroll
            for (int r = 0; r < 16; ++r) {
                float t  = (acc0[r] + acc1[r]) - nv;
                bool  gt = t > bv[r];
                bv[r] = gt ? t : bv[r];
                bi[r] = gt ? col : bi[r];
            }
        }
    }

    // Reduce across the 32 lanes (ln31) sharing each row; stride 33 words.
    __syncthreads();
    float* redv = (float*)(sm + 18432);        // [128][33] over eb region
    int*   redi = (int*)(sm + 18432) + 4224;   // [128][33]
#pragma unroll
    for (int r = 0; r < 16; ++r) {
        int row = (r & 3) + 8 * (r >> 2) + 4 * q + 32 * w;
        redv[row * 33 + ln31] = bv[r];
        redi[row * 33 + ln31] = bi[r];
    }
    __syncthreads();
    if (tid < 128) {
        float v  = redv[tid * 33];
        int   ix = redi[tid * 33];
#pragma unroll
        for (int j = 1; j < 32; ++j) {
            float vj = redv[tid * 33 + j];
            int   ij = redi[tid * 33 + j];
            if (vj > v) { v = vj; ix = ij; }
        }
        out[r0 + tid] = ix;
    }
}

// ---------------------------------------------------------------------------
extern "C" void kernel_launch(void* const* d_in, const int* in_sizes, int n_in,
                              void* d_out, int out_size, void* d_ws, size_t ws_size,
                              hipStream_t stream) {
    (void)n_in; (void)out_size; (void)ws_size;
    const float* x  = (const float*)d_in[0];
    const float* W1 = (const float*)d_in[1];
    const float* b1 = (const float*)d_in[2];
    const float* gm = (const float*)d_in[3];
    const float* bt = (const float*)d_in[4];
    const float* mu = (const float*)d_in[5];
    const float* vr = (const float*)d_in[6];
    const float* W2 = (const float*)d_in[7];
    const float* b2 = (const float*)d_in[8];
    const float* W3 = (const float*)d_in[9];
    const float* b3 = (const float*)d_in[10];
    const float* cb = (const float*)d_in[11];

    // Workspace layout (17.1 MB): norms | cbh | cbl | Zh | Zl
    float* norms = (float*)d_ws;                                        // 16 KB
    f16*   cbh   = (f16*)((char*)d_ws + 16384);                         // 512 KB
    f16*   cbl   = (f16*)((char*)d_ws + 16384 + 524288);                // 512 KB
    f16*   Zh    = (f16*)((char*)d_ws + 16384 + 2 * 524288);            // 8 MB
    f16*   Zl    = (f16*)((char*)d_ws + 16384 + 2 * 524288 + 8388608);  // 8 MB
    int*   out   = (int*)d_out;

    const int B = in_sizes[0] / IN_DIM;  // 65536

    k_norms<<<K_CODES / 256, 256, 0, stream>>>(cb, norms);
    k_cvt<<<K_CODES * EMB_DIM / 256, 256, 0, stream>>>(cb, cbh, cbl);
    k_encoder<<<B / 32, 256, 0, stream>>>(x, W1, b1, gm, bt, mu, vr, W2, b2, W3, b3, Zh, Zl);
    k_argmin_mfma<<<B / 128, 256, 0, stream>>>(Zh, Zl, cbh, cbl, norms, out);
}

// Round 6
// 294.411 us; speedup vs baseline: 13.9669x; 1.6091x over previous
//
#include <hip/hip_runtime.h>

// Problem constants (fixed by reference)
#define IN_DIM  256
#define HID_DIM 256
#define H2_DIM  128
#define EMB_DIM 64
#define K_CODES 4096
#define EPS_BN  1e-5f

// R3: __launch_bounds__(256,N) VGPR-clamps -> spill. R4: full unroll of big
// fragment loops -> scheduler hoists loads -> spill; unroll<=2 fixes.
// R5: argmin on matrix pipe via fp16 hi/lo split (3 MFMA passes ~ fp32
// fidelity) -> 604->205us, absmax 0. R6: same split for the encoder's three
// GEMMs, fused in one kernel with LDS round-trips between stages.

typedef _Float16 f16;
typedef _Float16 f16x4 __attribute__((ext_vector_type(4)));
typedef _Float16 f16x8 __attribute__((ext_vector_type(8)));
typedef float    f32x16 __attribute__((ext_vector_type(16)));

// ---------------------------------------------------------------------------
// Kernel 0a: half squared norms of codebook rows: norms[c] = 0.5*||e_c||^2
// ---------------------------------------------------------------------------
__global__ __launch_bounds__(256) void k_norms(const float* __restrict__ cb,
                                               float* __restrict__ norms) {
    int c = blockIdx.x * 256 + threadIdx.x;
    const float4* row = reinterpret_cast<const float4*>(cb + (size_t)c * EMB_DIM);
    float s = 0.f;
#pragma unroll
    for (int i = 0; i < EMB_DIM / 4; ++i) {
        float4 v = row[i];
        s += v.x * v.x + v.y * v.y + v.z * v.z + v.w * v.w;
    }
    norms[c] = 0.5f * s;
}

// ---------------------------------------------------------------------------
// Kernel 0b: split W1/W2/W3/codebook into fp16 hi/lo planes.
// Unified index: [0,65536) W1 | [.,98304) W2 | [.,106496) W3 | [.,368640) cb
// ---------------------------------------------------------------------------
__global__ __launch_bounds__(256) void k_prep(
    const float* __restrict__ W1, const float* __restrict__ W2,
    const float* __restrict__ W3, const float* __restrict__ cb,
    f16* __restrict__ w1h, f16* __restrict__ w1l,
    f16* __restrict__ w2h, f16* __restrict__ w2l,
    f16* __restrict__ w3h, f16* __restrict__ w3l,
    f16* __restrict__ cbh, f16* __restrict__ cbl) {
    int i = blockIdx.x * 256 + threadIdx.x;   // < 368640
    const float* src; f16 *dh, *dl; int off;
    if (i < 65536)       { src = W1; dh = w1h; dl = w1l; off = i; }
    else if (i < 98304)  { src = W2; dh = w2h; dl = w2l; off = i - 65536; }
    else if (i < 106496) { src = W3; dh = w3h; dl = w3l; off = i - 98304; }
    else                 { src = cb; dh = cbh; dl = cbl; off = i - 106496; }
    float v = src[off];
    f16 h = (f16)v;
    dh[off] = h;
    dl[off] = (f16)(v - (float)h);
}

// ---------------------------------------------------------------------------
// Kernel 1: fused MFMA encoder. 32 rows/block, 256 threads (4 waves).
// All GEMMs as v_mfma_f32_32x32x16_f16, 3 passes (hh, lh, hl) per k-step.
// Layouts (verified by R5 argmin): A[m=lane&31][k=q*8+j]; B[n=lane&31][k]
// (i.e. B-frag rows indexed by output col); C: col=lane&31,
// row=(reg&3)+8*(reg>>2)+4*q, q=lane>>5.
// LDS strides: 40 f16 (k-chunk 32) / 264 f16 (h1) / 136 f16 (h2,W3) — all
// == 4 mod 32 words -> conflict-free b128 fragment reads.
// Peak LDS 27136 f16 = 53.0 KB -> 3 blocks/CU.
// ---------------------------------------------------------------------------
__global__ __launch_bounds__(256) void k_encoder_mfma(
    const float* __restrict__ x,
    const f16* __restrict__ w1h, const f16* __restrict__ w1l,
    const f16* __restrict__ w2h, const f16* __restrict__ w2l,
    const f16* __restrict__ w3h, const f16* __restrict__ w3l,
    const float* __restrict__ b1,
    const float* __restrict__ gm, const float* __restrict__ bt,
    const float* __restrict__ mu, const float* __restrict__ vr,
    const float* __restrict__ b2, const float* __restrict__ b3,
    f16* __restrict__ Zh, f16* __restrict__ Zl) {
    __shared__ __align__(16) f16 sm[27136];  // 53.0 KB
    // Stage-1 staging:  xh@0[1280] xl@1280 w1h@2560[10240] w1l@12800
    // h1 planes:        h1h@0[8448] h1l@8448   (stride 264)
    // W2 staging:       w2h@16896[5120] w2l@22016
    // Stage-3 region:   h2h@0[4352] h2l@4352 (stride 136); w3h@8704[8704] w3l@17408
    const int tid  = threadIdx.x;
    const int lane = tid & 63;
    const int w    = tid >> 6;
    const int ln31 = lane & 31;
    const int q    = lane >> 5;
    const int r0   = blockIdx.x * 32;

    // ================= Stage 1: h1 = BN+ReLU(x @ W1^T) ======================
    f32x16 acc1a = {};
    f32x16 acc1b = {};
#pragma unroll 1
    for (int kc = 0; kc < 8; ++kc) {
        __syncthreads();
        // stage x chunk [32 r][32 k] -> hi/lo (convert fp32->f16 pair)
        {
            int row = tid >> 3, c = (tid & 7) * 4;
            float4 v = *reinterpret_cast<const float4*>(
                x + (size_t)(r0 + row) * IN_DIM + kc * 32 + c);
            f16x4 hv, lv;
            hv[0] = (f16)v.x; lv[0] = (f16)(v.x - (float)hv[0]);
            hv[1] = (f16)v.y; lv[1] = (f16)(v.y - (float)hv[1]);
            hv[2] = (f16)v.z; lv[2] = (f16)(v.z - (float)hv[2]);
            hv[3] = (f16)v.w; lv[3] = (f16)(v.w - (float)hv[3]);
            *(f16x4*)(sm + row * 40 + c)        = hv;
            *(f16x4*)(sm + 1280 + row * 40 + c) = lv;
        }
        // stage W1 chunk [256 j][32 k] hi/lo from pre-split planes
#pragma unroll
        for (int it = 0; it < 4; ++it) {
            int i = it * 256 + tid;
            int j = i >> 2, c8 = (i & 3) * 8;
            *(f16x8*)(sm + 2560 + j * 40 + c8) =
                *(const f16x8*)(w1h + j * IN_DIM + kc * 32 + c8);
            *(f16x8*)(sm + 12800 + j * 40 + c8) =
                *(const f16x8*)(w1l + j * IN_DIM + kc * 32 + c8);
        }
        __syncthreads();
#pragma unroll
        for (int ks = 0; ks < 2; ++ks) {
            f16x8 ah = *(const f16x8*)(sm + ln31 * 40 + ks * 16 + q * 8);
            f16x8 al = *(const f16x8*)(sm + 1280 + ln31 * 40 + ks * 16 + q * 8);
            int j0 = (w * 64 + ln31) * 40 + ks * 16 + q * 8;
            f16x8 bh0 = *(const f16x8*)(sm + 2560 + j0);
            f16x8 bl0 = *(const f16x8*)(sm + 12800 + j0);
            f16x8 bh1 = *(const f16x8*)(sm + 2560 + j0 + 32 * 40);
            f16x8 bl1 = *(const f16x8*)(sm + 12800 + j0 + 32 * 40);
            acc1a = __builtin_amdgcn_mfma_f32_32x32x16_f16(ah, bh0, acc1a, 0, 0, 0);
            acc1b = __builtin_amdgcn_mfma_f32_32x32x16_f16(ah, bh1, acc1b, 0, 0, 0);
            acc1a = __builtin_amdgcn_mfma_f32_32x32x16_f16(al, bh0, acc1a, 0, 0, 0);
            acc1b = __builtin_amdgcn_mfma_f32_32x32x16_f16(al, bh1, acc1b, 0, 0, 0);
            acc1a = __builtin_amdgcn_mfma_f32_32x32x16_f16(ah, bl0, acc1a, 0, 0, 0);
            acc1b = __builtin_amdgcn_mfma_f32_32x32x16_f16(ah, bl1, acc1b, 0, 0, 0);
        }
    }
    __syncthreads();  // stage-1 LDS reads done; region becomes h1 planes

    // BN + ReLU epilogue; write h1 hi/lo planes (stride 264).
    {
#pragma unroll
        for (int nt = 0; nt < 2; ++nt) {
            int j = w * 64 + nt * 32 + ln31;
            float sc = gm[j] * rsqrtf(vr[j] + EPS_BN);
            float sh = (b1[j] - mu[j]) * sc + bt[j];
            const f32x16& a = nt ? acc1b : acc1a;
#pragma unroll
            for (int r = 0; r < 16; ++r) {
                int row = (r & 3) + 8 * (r >> 2) + 4 * q;
                float v = a[r] * sc + sh;
                v = v > 0.f ? v : 0.f;
                f16 h = (f16)v;
                sm[row * 264 + j]        = h;
                sm[8448 + row * 264 + j] = (f16)(v - (float)h);
            }
        }
    }

    // ================= Stage 2: h2 = ReLU(h1 @ W2^T + b2) ===================
    f32x16 acc2a = {};
    f32x16 acc2b = {};
#pragma unroll 1
    for (int kc = 0; kc < 8; ++kc) {
        __syncthreads();
        // stage W2 chunk [128 j2][32 k] hi/lo
#pragma unroll
        for (int it = 0; it < 2; ++it) {
            int i = it * 256 + tid;
            int j = i >> 2, c8 = (i & 3) * 8;
            *(f16x8*)(sm + 16896 + j * 40 + c8) =
                *(const f16x8*)(w2h + j * HID_DIM + kc * 32 + c8);
            *(f16x8*)(sm + 22016 + j * 40 + c8) =
                *(const f16x8*)(w2l + j * HID_DIM + kc * 32 + c8);
        }
        __syncthreads();
#pragma unroll
        for (int ks = 0; ks < 2; ++ks) {
            f16x8 ah = *(const f16x8*)(sm + ln31 * 264 + kc * 32 + ks * 16 + q * 8);
            f16x8 al = *(const f16x8*)(sm + 8448 + ln31 * 264 + kc * 32 + ks * 16 + q * 8);
            int j0 = (w * 32 + ln31) * 40 + ks * 16 + q * 8;
            f16x8 bh = *(const f16x8*)(sm + 16896 + j0);
            f16x8 bl = *(const f16x8*)(sm + 22016 + j0);
            f32x16& acc = ks ? acc2b : acc2a;
            acc = __builtin_amdgcn_mfma_f32_32x32x16_f16(ah, bh, acc, 0, 0, 0);
            acc = __builtin_amdgcn_mfma_f32_32x32x16_f16(al, bh, acc, 0, 0, 0);
            acc = __builtin_amdgcn_mfma_f32_32x32x16_f16(ah, bl, acc, 0, 0, 0);
        }
    }
    __syncthreads();  // stage-2 LDS reads done; region becomes h2 + W3

    // ReLU epilogue -> h2 planes (stride 136); stage W3 [64 j3][128 k] hi/lo.
    {
        int j2 = w * 32 + ln31;
        float bias = b2[j2];
#pragma unroll
        for (int r = 0; r < 16; ++r) {
            int row = (r & 3) + 8 * (r >> 2) + 4 * q;
            float v = (acc2a[r] + acc2b[r]) + bias;
            v = v > 0.f ? v : 0.f;
            f16 h = (f16)v;
            sm[row * 136 + j2]        = h;
            sm[4352 + row * 136 + j2] = (f16)(v - (float)h);
        }
#pragma unroll
        for (int it = 0; it < 4; ++it) {
            int i = it * 256 + tid;
            int j = i >> 4, c8 = (i & 15) * 8;
            *(f16x8*)(sm + 8704 + j * 136 + c8) =
                *(const f16x8*)(w3h + j * H2_DIM + c8);
            *(f16x8*)(sm + 17408 + j * 136 + c8) =
                *(const f16x8*)(w3l + j * H2_DIM + c8);
        }
    }
    __syncthreads();

    // ================= Stage 3: z = tanh(h2 @ W3^T + b3) ====================
    if (w < 2) {  // 64 output cols -> waves 0,1 only
        f32x16 acc3a = {};
        f32x16 acc3b = {};
#pragma unroll 2
        for (int ks = 0; ks < 8; ++ks) {
            f16x8 ah = *(const f16x8*)(sm + ln31 * 136 + ks * 16 + q * 8);
            f16x8 al = *(const f16x8*)(sm + 4352 + ln31 * 136 + ks * 16 + q * 8);
            int j0 = 8704 + (w * 32 + ln31) * 136 + ks * 16 + q * 8;
            f16x8 bh = *(const f16x8*)(sm + j0);
            f16x8 bl = *(const f16x8*)(sm + j0 + 8704);
            f32x16& acc = (ks & 1) ? acc3b : acc3a;
            acc = __builtin_amdgcn_mfma_f32_32x32x16_f16(ah, bh, acc, 0, 0, 0);
            acc = __builtin_amdgcn_mfma_f32_32x32x16_f16(al, bh, acc, 0, 0, 0);
            acc = __builtin_amdgcn_mfma_f32_32x32x16_f16(ah, bl, acc, 0, 0, 0);
        }
        int j3 = w * 32 + ln31;
        float bias = b3[j3];
#pragma unroll
        for (int r = 0; r < 16; ++r) {
            int row = (r & 3) + 8 * (r >> 2) + 4 * q;
            float zv = tanhf((acc3a[r] + acc3b[r]) + bias);
            f16 h = (f16)zv;
            size_t idx = (size_t)(r0 + row) * EMB_DIM + j3;
            Zh[idx] = h;
            Zl[idx] = (f16)(zv - (float)h);
        }
    }
}

// ---------------------------------------------------------------------------
// Kernel 2: MFMA argmin (unchanged from R5 — proven). 128 rows/block.
// score(r,c) = z_r.e_c - 0.5||e_c||^2, maximized == argmin distance.
// ---------------------------------------------------------------------------
__global__ __launch_bounds__(256) void k_argmin_mfma(
    const f16* __restrict__ Zh, const f16* __restrict__ Zl,
    const f16* __restrict__ cbh, const f16* __restrict__ cbl,
    const float* __restrict__ norms, int* __restrict__ out) {
    __shared__ __align__(16) f16 sm[37120];  // 74.2 KB -> 2 blocks/CU
    f16* zh  = sm;            // [128][72]
    f16* zl  = sm + 9216;     // [128][72]
    f16* ebh = sm + 18432;    // [128][72]
    f16* ebl = sm + 27648;    // [128][72]
    float* nbuf = (float*)(sm + 36864);  // [128]
    const int tid  = threadIdx.x;
    const int lane = tid & 63;
    const int w    = tid >> 6;
    const int ln31 = lane & 31;
    const int q    = lane >> 5;
    const int r0   = blockIdx.x * 128;

    {
        const float4* srch = (const float4*)(Zh + (size_t)r0 * EMB_DIM);
        const float4* srcl = (const float4*)(Zl + (size_t)r0 * EMB_DIM);
        float4* dsth = (float4*)zh;
        float4* dstl = (float4*)zl;
#pragma unroll
        for (int it = 0; it < 4; ++it) {
            int i = it * 256 + tid;
            int row = i >> 3, c8 = i & 7;
            dsth[row * 9 + c8] = srch[row * 8 + c8];
            dstl[row * 9 + c8] = srcl[row * 8 + c8];
        }
    }
    __syncthreads();

    f16x8 ah[4], al[4];
#pragma unroll
    for (int ks = 0; ks < 4; ++ks) {
        int off = (w * 32 + ln31) * 72 + ks * 16 + q * 8;
        ah[ks] = *(const f16x8*)(zh + off);
        al[ks] = *(const f16x8*)(zl + off);
    }

    float bv[16];
    int   bi[16];
#pragma unroll
    for (int i = 0; i < 16; ++i) { bv[i] = -3.4e38f; bi[i] = 0; }

    for (int ch = 0; ch < K_CODES / 128; ++ch) {
        __syncthreads();
        const float4* srch = (const float4*)(cbh + (size_t)ch * 128 * EMB_DIM);
        const float4* srcl = (const float4*)(cbl + (size_t)ch * 128 * EMB_DIM);
        float4* dsth = (float4*)ebh;
        float4* dstl = (float4*)ebl;
#pragma unroll
        for (int it = 0; it < 4; ++it) {
            int i = it * 256 + tid;
            int row = i >> 3, c8 = i & 7;
            dsth[row * 9 + c8] = srch[row * 8 + c8];
            dstl[row * 9 + c8] = srcl[row * 8 + c8];
        }
        if (tid < 128) nbuf[tid] = norms[ch * 128 + tid];
        __syncthreads();

#pragma unroll 1
        for (int ct = 0; ct < 4; ++ct) {
            f16x8 bh[4], bl[4];
#pragma unroll
            for (int ks = 0; ks < 4; ++ks) {
                int off = (ct * 32 + ln31) * 72 + ks * 16 + q * 8;
                bh[ks] = *(const f16x8*)(ebh + off);
                bl[ks] = *(const f16x8*)(ebl + off);
            }
            f32x16 acc0 = {};
            f32x16 acc1 = {};
#pragma unroll
            for (int ks = 0; ks < 4; ks += 2) {
                acc0 = __builtin_amdgcn_mfma_f32_32x32x16_f16(ah[ks],     bh[ks],     acc0, 0, 0, 0);
                acc1 = __builtin_amdgcn_mfma_f32_32x32x16_f16(ah[ks + 1], bh[ks + 1], acc1, 0, 0, 0);
                acc0 = __builtin_amdgcn_mfma_f32_32x32x16_f16(al[ks],     bh[ks],     acc0, 0, 0, 0);
                acc1 = __builtin_amdgcn_mfma_f32_32x32x16_f16(al[ks + 1], bh[ks + 1], acc1, 0, 0, 0);
                acc0 = __builtin_amdgcn_mfma_f32_32x32x16_f16(ah[ks],     bl[ks],     acc0, 0, 0, 0);
                acc1 = __builtin_amdgcn_mfma_f32_32x32x16_f16(ah[ks + 1], bl[ks + 1], acc1, 0, 0, 0);
            }
            float nv  = nbuf[ct * 32 + ln31];
            int   col = ch * 128 + ct * 32 + ln31;
#pragma unroll
            for (int r = 0; r < 16; ++r) {
                float t  = (acc0[r] + acc1[r]) - nv;
                bool  gt = t > bv[r];
                bv[r] = gt ? t : bv[r];
                bi[r] = gt ? col : bi[r];
            }
        }
    }

    __syncthreads();
    float* redv = (float*)(sm + 18432);        // [128][33]
    int*   redi = (int*)(sm + 18432) + 4224;   // [128][33]
#pragma unroll
    for (int r = 0; r < 16; ++r) {
        int row = (r & 3) + 8 * (r >> 2) + 4 * q + 32 * w;
        redv[row * 33 + ln31] = bv[r];
        redi[row * 33 + ln31] = bi[r];
    }
    __syncthreads();
    if (tid < 128) {
        float v  = redv[tid * 33];
        int   ix = redi[tid * 33];
#pragma unroll
        for (int j = 1; j < 32; ++j) {
            float vj = redv[tid * 33 + j];
            int   ij = redi[tid * 33 + j];
            if (vj > v) { v = vj; ix = ij; }
        }
        out[r0 + tid] = ix;
    }
}

// ---------------------------------------------------------------------------
extern "C" void kernel_launch(void* const* d_in, const int* in_sizes, int n_in,
                              void* d_out, int out_size, void* d_ws, size_t ws_size,
                              hipStream_t stream) {
    (void)n_in; (void)out_size; (void)ws_size;
    const float* x  = (const float*)d_in[0];
    const float* W1 = (const float*)d_in[1];
    const float* b1 = (const float*)d_in[2];
    const float* gm = (const float*)d_in[3];
    const float* bt = (const float*)d_in[4];
    const float* mu = (const float*)d_in[5];
    const float* vr = (const float*)d_in[6];
    const float* W2 = (const float*)d_in[7];
    const float* b2 = (const float*)d_in[8];
    const float* W3 = (const float*)d_in[9];
    const float* b3 = (const float*)d_in[10];
    const float* cb = (const float*)d_in[11];

    // Workspace layout (~17.4 MB)
    char* ws = (char*)d_ws;
    float* norms = (float*)ws;                    // 16 KB
    f16* cbh = (f16*)(ws + 16384);                // 512 KB
    f16* cbl = (f16*)(ws + 540672);               // 512 KB
    f16* w1h = (f16*)(ws + 1064960);              // 128 KB
    f16* w1l = (f16*)(ws + 1196032);              // 128 KB
    f16* w2h = (f16*)(ws + 1327104);              // 64 KB
    f16* w2l = (f16*)(ws + 1392640);              // 64 KB
    f16* w3h = (f16*)(ws + 1458176);              // 16 KB
    f16* w3l = (f16*)(ws + 1474560);              // 16 KB
    f16* Zh  = (f16*)(ws + 1490944);              // 8 MB
    f16* Zl  = (f16*)(ws + 9879552);              // 8 MB
    int* out = (int*)d_out;

    const int B = in_sizes[0] / IN_DIM;  // 65536

    k_norms<<<K_CODES / 256, 256, 0, stream>>>(cb, norms);
    k_prep<<<1440, 256, 0, stream>>>(W1, W2, W3, cb, w1h, w1l, w2h, w2l,
                                     w3h, w3l, cbh, cbl);
    k_encoder_mfma<<<B / 32, 256, 0, stream>>>(x, w1h, w1l, w2h, w2l, w3h, w3l,
                                               b1, gm, bt, mu, vr, b2, b3, Zh, Zl);
    k_argmin_mfma<<<B / 128, 256, 0, stream>>>(Zh, Zl, cbh, cbl, norms, out);
}